// Round 20
// baseline (1220.973 us; speedup 1.0000x reference)
//
#include <hip/hip_runtime.h>
#include <hip/hip_bf16.h>

#define DDIM 1024
#define HDIM 4096
#define NEXP 8
#define NROW 8192
#define KPAIR 8192   // 2 experts * HDIM

typedef __attribute__((ext_vector_type(8))) short s16x8;
typedef __attribute__((ext_vector_type(4))) float f32x4;

using bf16 = __hip_bfloat16;

// ---------------------------------------------------------------- helpers
__device__ __forceinline__ void gload16(const bf16* g, bf16* lds) {
    __builtin_amdgcn_global_load_lds(
        (const __attribute__((address_space(1))) unsigned int*)g,
        (__attribute__((address_space(3))) unsigned int*)lds,
        16, 0, 0);
}

template <int N>
__device__ __forceinline__ void wait_vmcnt() {
    if constexpr (N == 6)      asm volatile("s_waitcnt vmcnt(6)" ::: "memory");
    else if constexpr (N == 3) asm volatile("s_waitcnt vmcnt(3)" ::: "memory");
    else                       asm volatile("s_waitcnt vmcnt(0)" ::: "memory");
}

// -------- fused x->bf16 convert + gate softmax + out = sum_e w[e]*b2[e,:]
__global__ void cvtgate_kernel(const float* __restrict__ x, const float* __restrict__ Wg,
                               const float* __restrict__ bg, const float* __restrict__ b2,
                               bf16* __restrict__ xb, float* __restrict__ wts,
                               float* __restrict__ out) {
    int wave = threadIdx.x >> 6, lane = threadIdx.x & 63;
    int n = blockIdx.x * 4 + wave;
    const float* xr = x + (size_t)n * DDIM;
    bf16* xbr = xb + (size_t)n * DDIM;
    float acc[NEXP] = {0.f, 0.f, 0.f, 0.f, 0.f, 0.f, 0.f, 0.f};
#pragma unroll
    for (int j = 0; j < 4; ++j) {
        int d0 = j * 256 + lane * 4;
        float4 v = *(const float4*)&xr[d0];
        union { bf16 b[4]; uint2 u; } pk;
        pk.b[0] = __float2bfloat16(v.x);
        pk.b[1] = __float2bfloat16(v.y);
        pk.b[2] = __float2bfloat16(v.z);
        pk.b[3] = __float2bfloat16(v.w);
        *(uint2*)&xbr[d0] = pk.u;
        const float* w0 = Wg + (size_t)d0 * NEXP;
#pragma unroll
        for (int e = 0; e < NEXP; ++e)
            acc[e] += v.x * w0[e] + v.y * w0[NEXP + e] + v.z * w0[2 * NEXP + e] +
                      v.w * w0[3 * NEXP + e];
    }
#pragma unroll
    for (int off = 32; off > 0; off >>= 1) {
#pragma unroll
        for (int e = 0; e < NEXP; ++e) acc[e] += __shfl_xor(acc[e], off, 64);
    }
    float mx = -1e30f;
#pragma unroll
    for (int e = 0; e < NEXP; ++e) { acc[e] += bg[e]; mx = fmaxf(mx, acc[e]); }
    float s = 0.f;
#pragma unroll
    for (int e = 0; e < NEXP; ++e) { acc[e] = __expf(acc[e] - mx); s += acc[e]; }
    float inv = 1.0f / s;
#pragma unroll
    for (int e = 0; e < NEXP; ++e) acc[e] *= inv;
    if (lane == 0) {
#pragma unroll
        for (int e = 0; e < NEXP; ++e) wts[(size_t)n * NEXP + e] = acc[e];
    }
    float* outr = out + (size_t)n * DDIM;
#pragma unroll
    for (int j = 0; j < 4; ++j) {
        int d0 = j * 256 + lane * 4;
        float4 sum = {0.f, 0.f, 0.f, 0.f};
#pragma unroll
        for (int e = 0; e < NEXP; ++e) {
            float4 bv = *(const float4*)&b2[(size_t)e * DDIM + d0];
            sum.x += acc[e] * bv.x;
            sum.y += acc[e] * bv.y;
            sum.z += acc[e] * bv.z;
            sum.w += acc[e] * bv.w;
        }
        *(float4*)&outr[d0] = sum;
    }
}

// ---------------- merged pair transpose: z<2 -> W1 expert z ([D][H]->[H][D]);
// z>=2 -> W2 expert z-2 ([H][D]-> cols of W2P [D][KPAIR]).
__global__ void transpose_pair_kernel(const float* __restrict__ W1s, bf16* __restrict__ W1d,
                                      const float* __restrict__ W2s, bf16* __restrict__ W2d) {
    __shared__ float t[128][65];
    const int z = blockIdx.z;
    const float* src; bf16* dst; int C, ldo, bx, by;
    if (z < 2) {
        src = W1s + (size_t)z * DDIM * HDIM;
        dst = W1d + (size_t)z * HDIM * DDIM;
        C = HDIM; ldo = DDIM;
        bx = blockIdx.x & 31; by = blockIdx.x >> 5;    // 32 x 16
    } else {
        src = W2s + (size_t)(z - 2) * HDIM * DDIM;
        dst = W2d + (size_t)(z - 2) * HDIM;
        C = DDIM; ldo = KPAIR;
        bx = blockIdx.x & 7; by = blockIdx.x >> 3;     // 8 x 64
    }
    const int r0 = by * 64, c0 = bx * 128;
    const int tid = threadIdx.x;
    const int lrow = tid >> 5, lc4 = tid & 31;
#pragma unroll
    for (int i = 0; i < 8; ++i) {
        int rr = i * 8 + lrow;
        float4 v = *(const float4*)&src[(size_t)(r0 + rr) * C + c0 + lc4 * 4];
        t[lc4 * 4 + 0][rr] = v.x;
        t[lc4 * 4 + 1][rr] = v.y;
        t[lc4 * 4 + 2][rr] = v.z;
        t[lc4 * 4 + 3][rr] = v.w;
    }
    __syncthreads();
    const int oc = tid >> 3, oj = tid & 7;
#pragma unroll
    for (int i = 0; i < 4; ++i) {
        int c = oc + i * 32;
        union { bf16 b[8]; s16x8 v; } p;
#pragma unroll
        for (int q = 0; q < 8; ++q) p.b[q] = __float2bfloat16(t[c][oj * 8 + q]);
        *(s16x8*)&dst[(size_t)(c0 + c) * ldo + r0 + oj * 8] = p.v;
    }
}

// ---------------------------------------------------------------- GEMM1 v2 (BK=64)
// BM=256 x BN=256, 8 waves 2(M)x4(N), wave-tile 128x64. PAIR-FUSED dispatch.
// ROUND-20: G2-v3 schedule ported — ONE barrier per K-tile, dbuf-2 with full
// 1-AHEAD prefetch into the OTHER buffer (no stage ever hits the active buf
// -> no intra-tile WAR -> intra-tile barriers removable). Stages issue at
// tile start -> full tile (~2000+ cyc MFMA) to land -> vmcnt(0) drain ~free.
// Per tile: {8 stages(t+1), 12 ds_reads(ks0), lgkm(4), 16 MFMA, lgkm(0),
// 16 MFMA, 12 ds_reads(ks1), lgkm(4), 16 MFMA, lgkm(0), 16 MFMA, vmcnt(0),
// barrier}. Barriers 4 -> 1 per K-tile (64 MFMA/barrier).
__global__ __launch_bounds__(512, 1) void gemm1(
    const bf16* __restrict__ A, const bf16* __restrict__ BTp, bf16* __restrict__ Hsb,
    const float* __restrict__ b1p, const float* __restrict__ wts,
    int lda, int ldb, int ldc, int NT, int tilesM, int tilesN, int XGN, int e0) {
    constexpr int WROWS = 128;
    constexpr int HALFA = 256 * 32;
    constexpr int HALFB = 256 * 32;
    constexpr int ATOT = 2 * HALFA;
    constexpr int BUFE = ATOT + 2 * HALFB;  // 32768 elems
    __shared__ __align__(16) bf16 smem[2 * BUFE];

    const int tid = threadIdx.x;
    const int wave = tid >> 6, lane = tid & 63;
    const int wm = wave >> 2, wn = wave & 3;
    const int r = lane & 15, kg = lane >> 4;

    const int eh = blockIdx.x >> 9;
    const int bx = blockIdx.x & 511;
    const bf16* BT = BTp + (size_t)eh * HDIM * DDIM;
    bf16* Cout = Hsb + (size_t)eh * HDIM;
    const float* bias = b1p + (size_t)eh * HDIM;
    const int expert = e0 + eh;

    const int xcd = bx & 7, slot = bx >> 3;
    const int XGM = 8 / XGN;
    const int rm = tilesM / XGM, rn = tilesN / XGN;
    const int g = slot >> 5, u = slot & 31;
    const int gpr = rn >> 3;
    const int gm = (g / gpr) * 4 + (u >> 3);
    const int gn = (g % gpr) * 8 + (u & 7);
    const int tm = (xcd / XGN) * rm + gm;
    const int tn = (xcd % XGN) * rn + gn;

    const bf16* gA = A + (size_t)tm * 256 * lda;
    const bf16* gB = BT + (size_t)tn * 256 * ldb;

    f32x4 acc[8][4];
#pragma unroll
    for (int m = 0; m < 8; ++m)
#pragma unroll
        for (int n = 0; n < 4; ++n) acc[m][n] = (f32x4){0.f, 0.f, 0.f, 0.f};

    auto stageA = [&](int t, int ks) {
        bf16* dst = smem + (t & 1) * BUFE + ks * HALFA;
#pragma unroll
        for (int j = 0; j < 2; ++j) {
            int c = j * 512 + tid;
            int R = c >> 2, kc = (c & 3) ^ ((R >> 1) & 3);
            gload16(gA + (size_t)R * lda + t * 64 + ks * 32 + kc * 8,
                    dst + (j * 512 + wave * 64) * 8);
        }
    };
    auto stageB = [&](int t, int ks) {
        bf16* dst = smem + (t & 1) * BUFE + ATOT + ks * HALFB;
#pragma unroll
        for (int j = 0; j < 2; ++j) {
            int c = j * 512 + tid;
            int R = c >> 2, kc = (c & 3) ^ ((R >> 1) & 3);
            gload16(gB + (size_t)R * ldb + t * 64 + ks * 32 + kc * 8,
                    dst + (j * 512 + wave * 64) * 8);
        }
    };

    s16x8 aLo[4], aHi[4], bb[4];
    auto ldALo = [&](int buf, int ks) {
#pragma unroll
        for (int m = 0; m < 4; ++m) {
            int R = wm * WROWS + m * 16 + r;
            aLo[m] = *(const s16x8*)&smem[buf * BUFE + ks * HALFA + R * 32 +
                                          ((kg ^ ((R >> 1) & 3)) * 8)];
        }
    };
    auto ldAHi = [&](int buf, int ks) {
#pragma unroll
        for (int m = 0; m < 4; ++m) {
            int R = wm * WROWS + 64 + m * 16 + r;
            aHi[m] = *(const s16x8*)&smem[buf * BUFE + ks * HALFA + R * 32 +
                                          ((kg ^ ((R >> 1) & 3)) * 8)];
        }
    };
    auto ldB = [&](int buf, int ks) {
#pragma unroll
        for (int n = 0; n < 4; ++n) {
            int R = wn * 64 + n * 16 + r;
            bb[n] = *(const s16x8*)&smem[buf * BUFE + ATOT + ks * HALFB + R * 32 +
                                         ((kg ^ ((R >> 1) & 3)) * 8)];
        }
    };

    auto mfmaLo = [&]() {
#pragma unroll
        for (int m = 0; m < 4; ++m)
#pragma unroll
            for (int n = 0; n < 4; ++n)
                acc[m][n] = __builtin_amdgcn_mfma_f32_16x16x32_bf16(aLo[m], bb[n], acc[m][n], 0, 0, 0);
    };
    auto mfmaHi = [&]() {
#pragma unroll
        for (int m = 0; m < 4; ++m)
#pragma unroll
            for (int n = 0; n < 4; ++n)
                acc[4 + m][n] = __builtin_amdgcn_mfma_f32_16x16x32_bf16(aHi[m], bb[n], acc[4 + m][n], 0, 0, 0);
    };

    // prologue: stage tile 0 only (1-ahead schedule)
    stageA(0, 0); stageB(0, 0); stageA(0, 1); stageB(0, 1);
    wait_vmcnt<0>();
    __builtin_amdgcn_s_barrier();

    for (int t = 0; t < NT; ++t) {
        const int b = t & 1;
        // stage ALL of t+1 into the other buffer (8 insts) — issue first so
        // the loads get the whole tile to land
        if (t + 1 < NT) { stageA(t + 1, 0); stageB(t + 1, 0); stageA(t + 1, 1); stageB(t + 1, 1); }
        // ---- ks half 0: 12 reads (B, A-lo, A-hi)
        ldB(b, 0); ldALo(b, 0); ldAHi(b, 0);
        asm volatile("s_waitcnt lgkmcnt(4)" ::: "memory");   // B + A-lo resident
        __builtin_amdgcn_sched_barrier(0);
        __builtin_amdgcn_s_setprio(1);
        mfmaLo();
        __builtin_amdgcn_s_setprio(0);
        asm volatile("s_waitcnt lgkmcnt(0)" ::: "memory");   // A-hi resident
        __builtin_amdgcn_sched_barrier(0);
        __builtin_amdgcn_s_setprio(1);
        mfmaHi();
        __builtin_amdgcn_s_setprio(0);
        // ---- ks half 1: 12 reads
        ldB(b, 1); ldALo(b, 1); ldAHi(b, 1);
        asm volatile("s_waitcnt lgkmcnt(4)" ::: "memory");
        __builtin_amdgcn_sched_barrier(0);
        __builtin_amdgcn_s_setprio(1);
        mfmaLo();
        __builtin_amdgcn_s_setprio(0);
        asm volatile("s_waitcnt lgkmcnt(0)" ::: "memory");
        __builtin_amdgcn_sched_barrier(0);
        __builtin_amdgcn_s_setprio(1);
        mfmaHi();
        __builtin_amdgcn_s_setprio(0);
        // ---- single tile-boundary sync (stages had the whole tile to land)
        if (t + 1 < NT) {
            wait_vmcnt<0>();
            __builtin_amdgcn_s_barrier();
        }
    }

    // ---- epilogue: Hs = w * relu(acc + bias), LDS-buffered coalesced store.
    __builtin_amdgcn_s_barrier();            // all waves done with smem frags
    bf16* hs = smem;                         // 65536 elems == 256*256
    const int col0 = tn * 256 + wn * 64;
#pragma unroll
    for (int n = 0; n < 4; ++n) {
        float bv = bias[col0 + n * 16 + r];
        int cl = wn * 64 + n * 16 + r;
#pragma unroll
        for (int mf = 0; mf < 8; ++mf) {
#pragma unroll
            for (int j = 0; j < 4; ++j) {
                int rl = wm * WROWS + (mf >> 2) * 64 + (mf & 3) * 16 + kg * 4 + j;
                float wv = wts[((size_t)tm * 256 + rl) * NEXP + expert];
                float v = acc[mf][n][j] + bv;
                v = v > 0.f ? v : 0.f;
                hs[rl * 256 + (cl ^ ((rl & 7) << 3))] = __float2bfloat16(wv * v);
            }
        }
    }
    __builtin_amdgcn_s_barrier();
    asm volatile("s_waitcnt lgkmcnt(0)" ::: "memory");
    const size_t rbase = (size_t)tm * 256;
    const int cbase = tn * 256;
#pragma unroll
    for (int i2 = 0; i2 < 16; ++i2) {
        int rl = wave * 32 + i2 * 2 + (lane >> 5);
        int c8 = (lane & 31) * 8;
        s16x8 v = *(const s16x8*)&hs[rl * 256 + (c8 ^ ((rl & 7) << 3))];
        *(s16x8*)&Cout[(rbase + rl) * (size_t)ldc + cbase + c8] = v;
    }
}

// ---------------------------------------------------------------- GEMM2 v3 (expert-pair, K=8192)
// Round-18 structure (best measured): ONE barrier per K-tile, dbuf-2,
// 1-ahead prefetch into the other buffer, 2 blocks/CU partner coverage.
__global__ __launch_bounds__(256, 2) void gemm2p(
    const bf16* __restrict__ A, const bf16* __restrict__ BT, float* __restrict__ O,
    int lda, int ldb, int ldc, int NT, int tilesM, int tilesN, int XGN) {
    constexpr int HALFA = 128 * 32;          // 4096 elems (one ks half of A)
    constexpr int HALFB = 128 * 32;
    constexpr int ATOT = 2 * HALFA;
    constexpr int BUFE = ATOT + 2 * HALFB;   // 16384 elems = 32 KiB
    constexpr int RSTR = 68;
    __shared__ __align__(16) bf16 smem[2 * BUFE];   // 64 KiB

    const int tid = threadIdx.x;
    const int wave = tid >> 6, lane = tid & 63;
    const int ksw = wave & 1, wn = wave >> 1;
    const int r = lane & 15, kg = lane >> 4;

    const int xcd = blockIdx.x & 7, slot = blockIdx.x >> 3;
    const int XGM = 8 / XGN;
    const int rm = tilesM / XGM, rn = tilesN / XGN;
    const int g = slot >> 5, u = slot & 31;
    const int gpr = rn >> 3;
    const int gm = (g / gpr) * 4 + (u >> 3);
    const int gn = (g % gpr) * 8 + (u & 7);
    const int tm = (xcd / XGN) * rm + gm;
    const int tn = (xcd % XGN) * rn + gn;

    const bf16* gA = A + (size_t)tm * 128 * lda;
    const bf16* gB = BT + (size_t)tn * 128 * ldb;

    f32x4 acc[8][4];
#pragma unroll
    for (int m = 0; m < 8; ++m)
#pragma unroll
        for (int n = 0; n < 4; ++n) acc[m][n] = (f32x4){0.f, 0.f, 0.f, 0.f};

    auto stageA_rh = [&](int t, int rh) {
        bf16* base = smem + (t & 1) * BUFE;
#pragma unroll
        for (int j = 0; j < 2; ++j) {         // j == ks
            int c = j * 256 + tid;
            int Rl = (c >> 2) & 63;
            int R = rh * 64 + Rl;
            int kc = (c & 3) ^ ((R >> 1) & 3);
            gload16(gA + (size_t)R * lda + t * 64 + j * 32 + kc * 8,
                    base + j * HALFA + rh * 2048 + ((c & 255) - lane) * 8 + lane * 8);
        }
    };
    auto stageB = [&](int t) {
        bf16* base = smem + (t & 1) * BUFE + ATOT;
#pragma unroll
        for (int j = 0; j < 4; ++j) {
            int c = j * 256 + tid;
            int ks = c >> 9;
            int R = (c >> 2) & 127;
            int kc = (c & 3) ^ ((R >> 1) & 3);
            gload16(gB + (size_t)R * ldb + t * 64 + ks * 32 + kc * 8,
                    base + ks * HALFB + ((c & 511) - lane) * 8 + lane * 8);
        }
    };

    s16x8 a0[4], a1[4], bfr[4];
    auto ldA0 = [&](int b) {
#pragma unroll
        for (int m = 0; m < 4; ++m) {
            int R = m * 16 + r;
            a0[m] = *(const s16x8*)&smem[b * BUFE + ksw * HALFA + R * 32 +
                                         ((kg ^ ((R >> 1) & 3)) * 8)];
        }
    };
    auto ldA1 = [&](int b) {
#pragma unroll
        for (int m = 0; m < 4; ++m) {
            int R = 64 + m * 16 + r;
            a1[m] = *(const s16x8*)&smem[b * BUFE + ksw * HALFA + R * 32 +
                                         ((kg ^ ((R >> 1) & 3)) * 8)];
        }
    };
    auto ldB = [&](int b) {
#pragma unroll
        for (int n = 0; n < 4; ++n) {
            int R = wn * 64 + n * 16 + r;
            bfr[n] = *(const s16x8*)&smem[b * BUFE + ATOT + ksw * HALFB + R * 32 +
                                          ((kg ^ ((R >> 1) & 3)) * 8)];
        }
    };

    // prologue: stage tile 0 only (1-ahead schedule)
    stageA_rh(0, 0); stageA_rh(0, 1); stageB(0);
    wait_vmcnt<0>();
    __builtin_amdgcn_s_barrier();

    for (int t = 0; t < NT; ++t) {
        const int b = t & 1;
        ldB(b); ldA1(b); ldA0(b);
        if (t + 1 < NT) { stageA_rh(t + 1, 0); stageA_rh(t + 1, 1); stageB(t + 1); }
        asm volatile("s_waitcnt lgkmcnt(4)" ::: "memory");
        __builtin_amdgcn_sched_barrier(0);
        __builtin_amdgcn_s_setprio(1);
#pragma unroll
        for (int m = 0; m < 4; ++m)
#pragma unroll
            for (int n = 0; n < 4; ++n)
                acc[4 + m][n] = __builtin_amdgcn_mfma_f32_16x16x32_bf16(a1[m], bfr[n], acc[4 + m][n], 0, 0, 0);
        __builtin_amdgcn_s_setprio(0);
        asm volatile("s_waitcnt lgkmcnt(0)" ::: "memory");
        __builtin_amdgcn_sched_barrier(0);
        __builtin_amdgcn_s_setprio(1);
#pragma unroll
        for (int m = 0; m < 4; ++m)
#pragma unroll
            for (int n = 0; n < 4; ++n)
                acc[m][n] = __builtin_amdgcn_mfma_f32_16x16x32_bf16(a0[m], bfr[n], acc[m][n], 0, 0, 0);
        __builtin_amdgcn_s_setprio(0);
        if (t + 1 < NT) {
            wait_vmcnt<0>();
            __builtin_amdgcn_s_barrier();
        }
    }

    // ---- split cross-ksw reduce, two rounds, static acc indices
    __syncthreads();
    float* red = (float*)smem;
    const int zone = wn * (64 * RSTR);
    const int col0 = tn * 128 + wn * 64;
    const size_t row0 = (size_t)tm * 128;
    if (ksw == 1) {
#pragma unroll
        for (int mq = 0; mq < 4; ++mq)
#pragma unroll
            for (int n = 0; n < 4; ++n) {
                int rl = mq * 16 + kg * 4;
                int cl = n * 16 + r;
#pragma unroll
                for (int j = 0; j < 4; ++j)
                    red[zone + (rl + j) * RSTR + cl] = acc[mq][n][j];
            }
    }
    __syncthreads();
    if (ksw == 0) {
#pragma unroll
        for (int mq = 0; mq < 4; ++mq)
#pragma unroll
            for (int j = 0; j < 4; ++j) {
                int rl = mq * 16 + kg * 4 + j;
                size_t rr = row0 + rl;
#pragma unroll
                for (int n = 0; n < 4; ++n) {
                    int cl = n * 16 + r;
                    O[rr * (size_t)ldc + col0 + cl] += acc[mq][n][j] + red[zone + rl * RSTR + cl];
                }
            }
    }
    __syncthreads();
    if (ksw == 0) {
#pragma unroll
        for (int mq = 0; mq < 4; ++mq)
#pragma unroll
            for (int n = 0; n < 4; ++n) {
                int rl = mq * 16 + kg * 4;
                int cl = n * 16 + r;
#pragma unroll
                for (int j = 0; j < 4; ++j)
                    red[zone + (rl + j) * RSTR + cl] = acc[4 + mq][n][j];
            }
    }
    __syncthreads();
    if (ksw == 1) {
#pragma unroll
        for (int mq = 0; mq < 4; ++mq)
#pragma unroll
            for (int j = 0; j < 4; ++j) {
                int rl = mq * 16 + kg * 4 + j;
                size_t rr = row0 + 64 + rl;
#pragma unroll
                for (int n = 0; n < 4; ++n) {
                    int cl = n * 16 + r;
                    O[rr * (size_t)ldc + col0 + cl] += acc[4 + mq][n][j] + red[zone + rl * RSTR + cl];
                }
            }
    }
}

// ---------------------------------------------------------------- launch
extern "C" void kernel_launch(void* const* d_in, const int* in_sizes, int n_in,
                              void* d_out, int out_size, void* d_ws, size_t ws_size,
                              hipStream_t stream) {
    const float* x  = (const float*)d_in[0];
    const float* Wg = (const float*)d_in[1];
    const float* bg = (const float*)d_in[2];
    const float* W1 = (const float*)d_in[3];
    const float* b1 = (const float*)d_in[4];
    const float* W2 = (const float*)d_in[5];
    const float* b2 = (const float*)d_in[6];
    float* out = (float*)d_out;

    char* ws = (char*)d_ws;
    bf16* xb   = (bf16*)(ws);                          // 16 MiB  [N][D]
    bf16* W1P  = (bf16*)(ws + (16ull << 20));          // 16 MiB  [2][H][D] (pair)
    bf16* W2P  = (bf16*)(ws + (32ull << 20));          // 16 MiB  [D][KPAIR] (pair)
    bf16* Hs   = (bf16*)(ws + (48ull << 20));          // 128 MiB [N][KPAIR] (pair)
    float* wts = (float*)(ws + (176ull << 20));        // 256 KiB [N][E]

    // fused: x->bf16 + gate softmax + out = sum_e w*b2
    cvtgate_kernel<<<NROW / 4, 256, 0, stream>>>(x, Wg, bg, b2, xb, wts, out);

    for (int p = 0; p < 4; ++p) {
        // merged pair transposes: W1 (z=0,1) + W2 (z=2,3) in one dispatch
        transpose_pair_kernel<<<dim3(512, 1, 4), 256, 0, stream>>>(
            W1 + (size_t)2 * p * DDIM * HDIM, W1P,
            W2 + (size_t)2 * p * HDIM * DDIM, W2P);
        // GEMM1 (both experts): Hs[:, eh*H ..] = w * relu(x @ W1[e] + b1[e])
        gemm1<<<1024, 512, 0, stream>>>(
            xb, W1P, Hs, b1 + (size_t)2 * p * HDIM, wts,
            DDIM, DDIM, KPAIR, DDIM / 64, 32, 16, 2, 2 * p);
        // GEMM2 pair: out += Hs @ W2P^T  (M=8192, N=1024, K=8192; 512 blocks)
        gemm2p<<<512, 256, 0, stream>>>(
            Hs, W2P, out, KPAIR, KPAIR, DDIM, KPAIR / 64, 64, 8, 1);
    }
}